// Round 5
// baseline (376.443 us; speedup 1.0000x reference)
//
#include <hip/hip_runtime.h>
#include <math.h>

#define SEQ    2048
#define DMODEL 768
#define NHEAD  12
#define NEXP   8
#define IDIM   1024
#define ISH    2048
#define KVS    4
#define NE2    10   // 8 routed experts + 2 shared-expert halves

typedef unsigned short u16;
typedef short s16x8 __attribute__((ext_vector_type(8)));
typedef u16   u16x8 __attribute__((ext_vector_type(8)));
typedef float f32x4 __attribute__((ext_vector_type(4)));

#define MFMA_BF16(a, b, c) __builtin_amdgcn_mfma_f32_16x16x32_bf16((a), (b), (c), 0, 0, 0)

__device__ __forceinline__ void glds16(const void* g, void* l) {
  __builtin_amdgcn_global_load_lds(
      (const __attribute__((address_space(1))) unsigned int*)g,
      (__attribute__((address_space(3))) unsigned int*)l, 16, 0, 0);
}

__device__ __forceinline__ u16 f2b(float f) {  // fp32 -> bf16 RNE
  unsigned int u = __float_as_uint(f);
  unsigned int r = u + 0x7fffu + ((u >> 16) & 1u);
  return (u16)(r >> 16);
}
__device__ __forceinline__ float b2f(u16 v) {
  return __uint_as_float(((unsigned int)v) << 16);
}

#define CVT_BLOCKS 10752   // (3*786432 + 2*196608) / 256

// ---------------------------------------------------------------- prep: weight cvt + rmsnorm1
__global__ __launch_bounds__(256) void prep_kernel(
    const float* __restrict__ w1, const float* __restrict__ w3, const float* __restrict__ w2,
    const float* __restrict__ fc1, const float* __restrict__ fc2,
    u16* __restrict__ w1b, u16* __restrict__ w3b, u16* __restrict__ w2b,
    u16* __restrict__ fc1b, u16* __restrict__ fc2b, int* __restrict__ counts,
    const float* __restrict__ x, const float* __restrict__ norm1_w, u16* __restrict__ xnb) {
  __shared__ float red[256];
  const int tid = threadIdx.x;
  if (blockIdx.x < CVT_BLOCKS) {
    if (blockIdx.x == 0 && tid < 16) counts[tid] = 0;
    long i = (long)blockIdx.x * 256 + tid;
    const long NW8 = (long)NEXP * IDIM * DMODEL / 8;   // 786432
    const long NF8 = (long)ISH * DMODEL / 8;           // 196608
    const float* s; u16* d; long o;
    if      (i < NW8)             { s = w1;  d = w1b;  o = i; }
    else if (i < 2 * NW8)         { s = w3;  d = w3b;  o = i - NW8; }
    else if (i < 3 * NW8)         { s = w2;  d = w2b;  o = i - 2 * NW8; }
    else if (i < 3 * NW8 + NF8)   { s = fc1; d = fc1b; o = i - 3 * NW8; }
    else                          { s = fc2; d = fc2b; o = i - 3 * NW8 - NF8; }
    float4 a = ((const float4*)s)[2 * o], b = ((const float4*)s)[2 * o + 1];
    u16x8 v;
    v[0] = f2b(a.x); v[1] = f2b(a.y); v[2] = f2b(a.z); v[3] = f2b(a.w);
    v[4] = f2b(b.x); v[5] = f2b(b.y); v[6] = f2b(b.z); v[7] = f2b(b.w);
    ((u16x8*)d)[o] = v;
    return;
  }
  // rmsnorm branch
  const int row = blockIdx.x - CVT_BLOCKS;
  const float* r = x + (size_t)row * DMODEL;
  float v0 = r[tid], v1 = r[tid + 256], v2 = r[tid + 512];
  float ss = v0 * v0 + v1 * v1 + v2 * v2;
  red[tid] = ss;
  __syncthreads();
  for (int s = 128; s > 0; s >>= 1) {
    if (tid < s) red[tid] += red[tid + s];
    __syncthreads();
  }
  float rms = rsqrtf(red[0] * (1.f / DMODEL) + 1e-5f);
  u16* ob = xnb + (size_t)row * DMODEL;
  ob[tid]       = f2b(v0 * rms * norm1_w[tid]);
  ob[tid + 256] = f2b(v1 * rms * norm1_w[tid + 256]);
  ob[tid + 512] = f2b(v2 * rms * norm1_w[tid + 512]);
}

// ---------------------------------------------------------------- MFMA flash attention, kv-split
__global__ __launch_bounds__(256) void attn_kernel(const u16* __restrict__ xnb,
                                                   u16* __restrict__ Opart,
                                                   float* __restrict__ Mpart,
                                                   float* __restrict__ Lpart) {
  __shared__ u16 Qs[64][72];
  __shared__ u16 Ks[64][72];
  __shared__ u16 Vt[64][72];   // transposed V: [d][k]
  __shared__ u16 Ps[64][72];   // P in A-layout: [q][k]
  const int h = blockIdx.y, kvs = blockIdx.z;
  const int q0 = blockIdx.x * 64;
  const int tid = threadIdx.x;
  const int lane = tid & 63, w = tid >> 6;
  const int quad = lane >> 4, l15 = lane & 15;
  const size_t hoff = (size_t)h * 64;

  for (int cc = tid; cc < 512; cc += 256) {
    int row = cc >> 3, col8 = (cc & 7) * 8;
    *(u16x8*)&Qs[row][col8] = *(const u16x8*)(xnb + (size_t)(q0 + row) * DMODEL + hoff + col8);
  }
  __syncthreads();
  const s16x8 aq0 = *(const s16x8*)&Qs[16 * w + l15][quad * 8];
  const s16x8 aq1 = *(const s16x8*)&Qs[16 * w + l15][32 + quad * 8];

  f32x4 o[4] = {};
  float mrow[4], lrow[4];
#pragma unroll
  for (int r = 0; r < 4; r++) { mrow[r] = -INFINITY; lrow[r] = 0.f; }

  const int it0 = kvs * (SEQ / 64 / KVS);
  for (int it = 0; it < SEQ / 64 / KVS; it++) {
    const int k0 = (it0 + it) * 64;
    for (int cc = tid; cc < 512; cc += 256) {
      int row = cc >> 3, col8 = (cc & 7) * 8;
      *(u16x8*)&Ks[row][col8] = *(const u16x8*)(xnb + (size_t)(k0 + row) * DMODEL + hoff + col8);
    }
    __syncthreads();

    {
      const int rp = tid & 31, dc = ((tid >> 5) & 7) * 8;
      u16x8 v0 = *(const u16x8*)&Ks[2 * rp][dc];
      u16x8 v1 = *(const u16x8*)&Ks[2 * rp + 1][dc];
#pragma unroll
      for (int j = 0; j < 8; j++) {
        *(unsigned int*)&Vt[dc + j][2 * rp] =
            (unsigned int)v0[j] | ((unsigned int)v1[j] << 16);
      }
    }

    f32x4 s4[4] = {};
#pragma unroll
    for (int jt = 0; jt < 4; jt++) {
      s16x8 b0 = *(const s16x8*)&Ks[16 * jt + l15][quad * 8];
      s16x8 b1 = *(const s16x8*)&Ks[16 * jt + l15][32 + quad * 8];
      s4[jt] = MFMA_BF16(aq0, b0, s4[jt]);
      s4[jt] = MFMA_BF16(aq1, b1, s4[jt]);
      s4[jt] *= 0.125f;  // 1/sqrt(64)
    }

#pragma unroll
    for (int r = 0; r < 4; r++) {
      float mx = mrow[r];
#pragma unroll
      for (int jt = 0; jt < 4; jt++) mx = fmaxf(mx, s4[jt][r]);
#pragma unroll
      for (int m = 1; m <= 8; m <<= 1) mx = fmaxf(mx, __shfl_xor(mx, m, 64));
      float al = __expf(mrow[r] - mx);
      mrow[r] = mx;
      float pv[4], sum = 0.f;
#pragma unroll
      for (int jt = 0; jt < 4; jt++) { pv[jt] = __expf(s4[jt][r] - mx); sum += pv[jt]; }
#pragma unroll
      for (int m = 1; m <= 8; m <<= 1) sum += __shfl_xor(sum, m, 64);
      lrow[r] = lrow[r] * al + sum;
#pragma unroll
      for (int jt = 0; jt < 4; jt++) o[jt][r] *= al;
#pragma unroll
      for (int jt = 0; jt < 4; jt++) Ps[16 * w + quad * 4 + r][16 * jt + l15] = f2b(pv[jt]);
    }
    __syncthreads();

    s16x8 ap0 = *(const s16x8*)&Ps[16 * w + l15][quad * 8];
    s16x8 ap1 = *(const s16x8*)&Ps[16 * w + l15][32 + quad * 8];
#pragma unroll
    for (int jt = 0; jt < 4; jt++) {
      s16x8 bv0 = *(const s16x8*)&Vt[16 * jt + l15][quad * 8];
      s16x8 bv1 = *(const s16x8*)&Vt[16 * jt + l15][32 + quad * 8];
      o[jt] = MFMA_BF16(ap0, bv0, o[jt]);
      o[jt] = MFMA_BF16(ap1, bv1, o[jt]);
    }
  }

  const size_t base = ((size_t)kvs * NHEAD + h) * SEQ;
#pragma unroll
  for (int r = 0; r < 4; r++) {
    int q = q0 + 16 * w + quad * 4 + r;
#pragma unroll
    for (int jt = 0; jt < 4; jt++)
      Opart[(base + q) * 64 + 16 * jt + l15] = f2b(o[jt][r]);
    if (l15 == 0) {
      Mpart[base + q] = mrow[r];
      Lpart[base + q] = lrow[r];
    }
  }
}

// ---------------------------------------------------------------- fused post-attention
__global__ __launch_bounds__(256) void fused_post_kernel(
    const u16* __restrict__ Opart, const float* __restrict__ Mpart,
    const float* __restrict__ Lpart, const float* __restrict__ x,
    const float* __restrict__ n3w, const float* __restrict__ gw,
    u16* __restrict__ xfb, float* __restrict__ out,
    int* __restrict__ counts, int* __restrict__ toklist, float* __restrict__ wtlist) {
  const int t = blockIdx.x;
  const int tid = threadIdx.x;
  __shared__ float Ms[KVS * NHEAD], Ls[KVS * NHEAD];
  __shared__ float red[256];
  __shared__ float gred[4][NEXP];
  if (tid < KVS * NHEAD) {
    Ms[tid] = Mpart[(size_t)tid * SEQ + t];
    Ls[tid] = Lpart[(size_t)tid * SEQ + t];
  }
  __syncthreads();

  float val[3];
  float ss = 0.f;
#pragma unroll
  for (int ii = 0; ii < 3; ii++) {
    int c = tid + ii * 256;
    int h = c >> 6, d = c & 63;
    float M = -INFINITY;
#pragma unroll
    for (int k = 0; k < KVS; k++) M = fmaxf(M, Ms[k * NHEAD + h]);
    float L = 0.f, O = 0.f;
#pragma unroll
    for (int k = 0; k < KVS; k++) {
      float wgt = __expf(Ms[k * NHEAD + h] - M);
      L += wgt * Ls[k * NHEAD + h];
      O += wgt * b2f(Opart[((size_t)(k * NHEAD + h) * SEQ + t) * 64 + d]);
    }
    float v = x[(size_t)t * DMODEL + c] + O / L;
    out[(size_t)t * DMODEL + c] = v;
    val[ii] = v;
    ss += v * v;
  }
  red[tid] = ss;
  __syncthreads();
  for (int s = 128; s > 0; s >>= 1) {
    if (tid < s) red[tid] += red[tid + s];
    __syncthreads();
  }
  float rms = rsqrtf(red[0] * (1.f / DMODEL) + 1e-5f);

  float ge[NEXP] = {};
#pragma unroll
  for (int ii = 0; ii < 3; ii++) {
    int c = tid + ii * 256;
    float xn = val[ii] * rms * n3w[c];
    xfb[(size_t)t * DMODEL + c] = f2b(xn);
#pragma unroll
    for (int e = 0; e < NEXP; e++) ge[e] = fmaf(xn, gw[e * DMODEL + c], ge[e]);
  }
  const int lane = tid & 63, w = tid >> 6;
#pragma unroll
  for (int off = 32; off >= 1; off >>= 1)
#pragma unroll
    for (int e = 0; e < NEXP; e++) ge[e] += __shfl_xor(ge[e], off, 64);
  if (lane == 0)
#pragma unroll
    for (int e = 0; e < NEXP; e++) gred[w][e] = ge[e];
  __syncthreads();
  if (tid == 0) {
    float p[NEXP], mx = -INFINITY, s = 0.f;
#pragma unroll
    for (int e = 0; e < NEXP; e++) {
      p[e] = gred[0][e] + gred[1][e] + gred[2][e] + gred[3][e];
      mx = fmaxf(mx, p[e]);
    }
#pragma unroll
    for (int e = 0; e < NEXP; e++) { p[e] = __expf(p[e] - mx); s += p[e]; }
    int e0 = 0; float b0 = p[0];
    for (int e = 1; e < NEXP; e++) if (p[e] > b0) { b0 = p[e]; e0 = e; }
    int e1 = -1; float b1v = -1.f;
    for (int e = 0; e < NEXP; e++) if (e != e0 && p[e] > b1v) { b1v = p[e]; e1 = e; }
    float inv = 1.f / s;
    int pos0 = atomicAdd(&counts[e0], 1);
    toklist[e0 * SEQ + pos0] = t;
    wtlist[e0 * SEQ + pos0] = fmaxf(b0 * inv, 1e-7f);
    int pos1 = atomicAdd(&counts[e1], 1);
    toklist[e1 * SEQ + pos1] = t;
    wtlist[e1 * SEQ + pos1] = fmaxf(b1v * inv, 1e-7f);
  }
}

// ---------------------------------------------------------------- GEMM1: fused SwiGLU, 10 experts
// 64x128 tile, BK=64 (two 32-col panels), XCD-swizzled 1D grid (2560 blocks).
__global__ __launch_bounds__(256) void gemm1_kernel(
    const u16* __restrict__ xfb,
    const u16* __restrict__ w1b, const u16* __restrict__ w3b, const u16* __restrict__ fc1b,
    const float* __restrict__ b1, const float* __restrict__ b3, const float* __restrict__ fc1_b,
    const int* __restrict__ counts, const int* __restrict__ toklist, u16* __restrict__ hb) {
  __shared__ u16 As0[64][32],  As1[64][32];
  __shared__ u16 W1s0[128][32], W1s1[128][32];
  __shared__ u16 W3s0[128][32], W3s1[128][32];
  __shared__ int rIdx[64];
  // swizzle: XCD g gets contiguous tile chunk, n fastest -> A-tile L2 reuse
  const int L = blockIdx.x;                 // 0..2559
  const int g = L & 7, s = L >> 3;          // s: 0..319
  const int T = g * 320 + s;
  const int e = T >> 8;                     // 256 tiles/expert (32 m x 8 n)
  const int rem = T & 255;
  const int mt = rem >> 3, nt = rem & 7;
  const bool routed = (e < NEXP);
  int cnt, off;
  if (routed) {
    cnt = counts[e];
    off = 0;
    for (int i = 0; i < e; i++) off += counts[i];
  } else {
    cnt = SEQ;
    off = 2 * SEQ + (e - NEXP) * SEQ;
  }
  const int m0 = mt * 64;
  if (m0 >= cnt) return;
  const int n0 = nt * 128;
  const int tid = threadIdx.x;
  if (tid < 64) {
    int rr = m0 + tid;
    rIdx[tid] = routed ? toklist[e * SEQ + (rr < cnt ? rr : cnt - 1)] : rr;
  }
  __syncthreads();
  const u16* W1 = routed ? w1b + (size_t)e * IDIM * DMODEL
                         : fc1b + (size_t)(e - NEXP) * IDIM * DMODEL;
  const u16* W3 = w3b + (size_t)(routed ? e : 0) * IDIM * DMODEL;

  const int lane = tid & 63, w = tid >> 6;
  const int quad = lane >> 4, l15 = lane & 15;
  const int wy = w >> 1, wx = w & 1;
  const int rsub = lane >> 2, c8 = (lane & 3) * 8;
  const u16* Ap   = xfb + (size_t)rIdx[16 * w + rsub] * DMODEL + c8;
  const u16* W1p0 = W1 + (size_t)(n0 + 32 * w + rsub) * DMODEL + c8;
  const u16* W1p1 = W1 + (size_t)(n0 + 32 * w + 16 + rsub) * DMODEL + c8;
  const u16* W3p0 = W3 + (size_t)(n0 + 32 * w + rsub) * DMODEL + c8;
  const u16* W3p1 = W3 + (size_t)(n0 + 32 * w + 16 + rsub) * DMODEL + c8;

  f32x4 acc1[2][4] = {};
  f32x4 acc3[2][4] = {};
  for (int k0 = 0; k0 < DMODEL; k0 += 64) {
    glds16(Ap + k0,        &As0[16 * w][0]);
    glds16(Ap + k0 + 32,   &As1[16 * w][0]);
    glds16(W1p0 + k0,      &W1s0[32 * w][0]);
    glds16(W1p1 + k0,      &W1s0[32 * w + 16][0]);
    glds16(W1p0 + k0 + 32, &W1s1[32 * w][0]);
    glds16(W1p1 + k0 + 32, &W1s1[32 * w + 16][0]);
    if (routed) {
      glds16(W3p0 + k0,      &W3s0[32 * w][0]);
      glds16(W3p1 + k0,      &W3s0[32 * w + 16][0]);
      glds16(W3p0 + k0 + 32, &W3s1[32 * w][0]);
      glds16(W3p1 + k0 + 32, &W3s1[32 * w + 16][0]);
    }
    __syncthreads();
    s16x8 af0[2], af1[2], w1f0[4], w1f1[4];
#pragma unroll
    for (int i = 0; i < 2; i++) {
      af0[i] = *(const s16x8*)&As0[32 * wy + 16 * i + l15][quad * 8];
      af1[i] = *(const s16x8*)&As1[32 * wy + 16 * i + l15][quad * 8];
    }
#pragma unroll
    for (int j = 0; j < 4; j++) {
      w1f0[j] = *(const s16x8*)&W1s0[64 * wx + 16 * j + l15][quad * 8];
      w1f1[j] = *(const s16x8*)&W1s1[64 * wx + 16 * j + l15][quad * 8];
    }
#pragma unroll
    for (int i = 0; i < 2; i++)
#pragma unroll
      for (int j = 0; j < 4; j++) {
        acc1[i][j] = MFMA_BF16(af0[i], w1f0[j], acc1[i][j]);
        acc1[i][j] = MFMA_BF16(af1[i], w1f1[j], acc1[i][j]);
      }
    if (routed) {
      s16x8 w3f0[4], w3f1[4];
#pragma unroll
      for (int j = 0; j < 4; j++) {
        w3f0[j] = *(const s16x8*)&W3s0[64 * wx + 16 * j + l15][quad * 8];
        w3f1[j] = *(const s16x8*)&W3s1[64 * wx + 16 * j + l15][quad * 8];
      }
#pragma unroll
      for (int i = 0; i < 2; i++)
#pragma unroll
        for (int j = 0; j < 4; j++) {
          acc3[i][j] = MFMA_BF16(af0[i], w3f0[j], acc3[i][j]);
          acc3[i][j] = MFMA_BF16(af1[i], w3f1[j], acc3[i][j]);
        }
    }
    __syncthreads();
  }

#pragma unroll
  for (int j = 0; j < 4; j++) {
    int n = n0 + 64 * wx + 16 * j + l15;
    float b1v = routed ? b1[e * IDIM + n] : fc1_b[(e - NEXP) * IDIM + n];
    float b3v = routed ? b3[e * IDIM + n] : 0.f;
#pragma unroll
    for (int i = 0; i < 2; i++) {
#pragma unroll
      for (int r = 0; r < 4; r++) {
        int rr = m0 + 32 * wy + 16 * i + quad * 4 + r;
        if (rr < cnt) {
          float a = acc1[i][j][r] + b1v;
          float gg = routed ? (acc3[i][j][r] + b3v) : 1.f;
          float hv = a / (1.f + __expf(-a)) * gg;
          hb[(size_t)(off + rr) * IDIM + n] = f2b(hv);
        }
      }
    }
  }
}

// ---------------------------------------------------------------- GEMM2: down-proj, 10 experts
// 64x128 tile, BK=64, XCD-swizzled 1D grid (1920 blocks).
__global__ __launch_bounds__(256) void gemm2_kernel(
    const u16* __restrict__ hb,
    const u16* __restrict__ w2b, const u16* __restrict__ fc2b,
    const float* __restrict__ b2, const float* __restrict__ fc2_b,
    const int* __restrict__ counts, const int* __restrict__ toklist,
    const float* __restrict__ wtlist, float* __restrict__ out) {
  __shared__ u16 As0[64][32],  As1[64][32];
  __shared__ u16 Ws0[128][32], Ws1[128][32];
  const int L = blockIdx.x;                 // 0..1919
  const int g = L & 7, s = L >> 3;          // s: 0..239
  const int T = g * 240 + s;
  const int e = T / 192;                    // 192 tiles/expert (32 m x 6 n)
  const int rem = T - e * 192;
  const int mt = rem / 6, nt = rem - mt * 6;
  const bool routed = (e < NEXP);
  int cnt, off;
  if (routed) {
    cnt = counts[e];
    off = 0;
    for (int i = 0; i < e; i++) off += counts[i];
  } else {
    cnt = SEQ;
    off = 2 * SEQ + (e - NEXP) * SEQ;
  }
  const int m0 = mt * 64;
  if (m0 >= cnt) return;
  const int n0 = nt * 128;
  const int tid = threadIdx.x;

  const u16* Wb; int ldw, kof;
  if (routed) { Wb = w2b + (size_t)e * DMODEL * IDIM; ldw = IDIM; kof = 0; }
  else        { Wb = fc2b;                            ldw = ISH;  kof = (e - NEXP) * IDIM; }

  const int lane = tid & 63, w = tid >> 6;
  const int quad = lane >> 4, l15 = lane & 15;
  const int wy = w >> 1, wx = w & 1;
  const int rsub = lane >> 2, c8 = (lane & 3) * 8;
  int ra = m0 + 16 * w + rsub; ra = off + (ra < cnt ? ra : cnt - 1);
  const u16* Ap  = hb + (size_t)ra * IDIM + c8;
  const u16* Wp0 = Wb + (size_t)(n0 + 32 * w + rsub) * ldw + kof + c8;
  const u16* Wp1 = Wb + (size_t)(n0 + 32 * w + 16 + rsub) * ldw + kof + c8;

  f32x4 acc[2][4] = {};
  for (int k0 = 0; k0 < IDIM; k0 += 64) {
    glds16(Ap + k0,        &As0[16 * w][0]);
    glds16(Ap + k0 + 32,   &As1[16 * w][0]);
    glds16(Wp0 + k0,       &Ws0[32 * w][0]);
    glds16(Wp1 + k0,       &Ws0[32 * w + 16][0]);
    glds16(Wp0 + k0 + 32,  &Ws1[32 * w][0]);
    glds16(Wp1 + k0 + 32,  &Ws1[32 * w + 16][0]);
    __syncthreads();
    s16x8 af0[2], af1[2], wf0[4], wf1[4];
#pragma unroll
    for (int i = 0; i < 2; i++) {
      af0[i] = *(const s16x8*)&As0[32 * wy + 16 * i + l15][quad * 8];
      af1[i] = *(const s16x8*)&As1[32 * wy + 16 * i + l15][quad * 8];
    }
#pragma unroll
    for (int j = 0; j < 4; j++) {
      wf0[j] = *(const s16x8*)&Ws0[64 * wx + 16 * j + l15][quad * 8];
      wf1[j] = *(const s16x8*)&Ws1[64 * wx + 16 * j + l15][quad * 8];
    }
#pragma unroll
    for (int i = 0; i < 2; i++)
#pragma unroll
      for (int j = 0; j < 4; j++) {
        acc[i][j] = MFMA_BF16(af0[i], wf0[j], acc[i][j]);
        acc[i][j] = MFMA_BF16(af1[i], wf1[j], acc[i][j]);
      }
    __syncthreads();
  }

#pragma unroll
  for (int j = 0; j < 4; j++) {
    int n = n0 + 64 * wx + 16 * j + l15;
    float bv = routed ? b2[e * DMODEL + n] : (e == NEXP ? fc2_b[n] : 0.f);
#pragma unroll
    for (int i = 0; i < 2; i++) {
#pragma unroll
      for (int r = 0; r < 4; r++) {
        int rr = m0 + 32 * wy + 16 * i + quad * 4 + r;
        if (rr < cnt) {
          int tok; float wt;
          if (routed) { tok = toklist[e * SEQ + rr]; wt = wtlist[e * SEQ + rr]; }
          else        { tok = rr;                    wt = 1.f; }
          atomicAdd(&out[(size_t)tok * DMODEL + n], wt * (acc[i][j][r] + bv));
        }
      }
    }
  }
}

// ---------------------------------------------------------------- launch
extern "C" void kernel_launch(void* const* d_in, const int* in_sizes, int n_in,
                              void* d_out, int out_size, void* d_ws, size_t ws_size,
                              hipStream_t stream) {
  const float* x       = (const float*)d_in[0];
  const float* norm1_w = (const float*)d_in[1];
  const float* norm3_w = (const float*)d_in[2];
  const float* gate_w  = (const float*)d_in[3];
  const float* w1      = (const float*)d_in[4];
  const float* b1      = (const float*)d_in[5];
  const float* w2      = (const float*)d_in[6];
  const float* b2      = (const float*)d_in[7];
  const float* w3      = (const float*)d_in[8];
  const float* b3      = (const float*)d_in[9];
  const float* fc1_w   = (const float*)d_in[10];
  const float* fc1_b   = (const float*)d_in[11];
  const float* fc2_w   = (const float*)d_in[12];
  const float* fc2_b   = (const float*)d_in[13];
  float* out = (float*)d_out;

  // workspace layout
  char* p = (char*)d_ws;
  u16*   xnb    = (u16*)p;   p += (size_t)SEQ * DMODEL * 2;
  u16*   xfb    = (u16*)p;   p += (size_t)SEQ * DMODEL * 2;
  u16*   hb     = (u16*)p;   p += (size_t)4 * SEQ * IDIM * 2;        // 8192 slots
  u16*   Opart  = (u16*)p;   p += (size_t)KVS * NHEAD * SEQ * 64 * 2;
  float* Mpart  = (float*)p; p += (size_t)KVS * NHEAD * SEQ * 4;
  float* Lpart  = (float*)p; p += (size_t)KVS * NHEAD * SEQ * 4;
  u16*   w1b    = (u16*)p;   p += (size_t)NEXP * IDIM * DMODEL * 2;
  u16*   w3b    = (u16*)p;   p += (size_t)NEXP * IDIM * DMODEL * 2;
  u16*   w2b    = (u16*)p;   p += (size_t)NEXP * DMODEL * IDIM * 2;
  u16*   fc1b   = (u16*)p;   p += (size_t)ISH * DMODEL * 2;
  u16*   fc2b   = (u16*)p;   p += (size_t)DMODEL * ISH * 2;
  int*   counts = (int*)p;   p += 256;
  int*   toklist= (int*)p;   p += (size_t)NEXP * SEQ * 4;
  float* wtlist = (float*)p; p += (size_t)NEXP * SEQ * 4;

  prep_kernel<<<CVT_BLOCKS + SEQ, 256, 0, stream>>>(
      w1, w3, w2, fc1_w, fc2_w, w1b, w3b, w2b, fc1b, fc2b, counts, x, norm1_w, xnb);
  attn_kernel<<<dim3(SEQ / 64, NHEAD, KVS), 256, 0, stream>>>(xnb, Opart, Mpart, Lpart);
  fused_post_kernel<<<SEQ, 256, 0, stream>>>(Opart, Mpart, Lpart, x, norm3_w, gate_w,
                                             xfb, out, counts, toklist, wtlist);
  gemm1_kernel<<<2560, 256, 0, stream>>>(
      xfb, w1b, w3b, fc1b, b1, b3, fc1_b, counts, toklist, hb);
  gemm2_kernel<<<1920, 256, 0, stream>>>(
      hb, w2b, fc2b, b2, fc2_b, counts, toklist, wtlist, out);
  (void)in_sizes; (void)n_in; (void)out_size; (void)ws_size;
}